// Round 1
// baseline (287.372 us; speedup 1.0000x reference)
//
#include <hip/hip_runtime.h>
#include <hip/hip_bf16.h>

// Problem constants (from reference): C=91 classes, 90 foreground, 100 dets/img,
// FD=1024 features, BBOX clip = log(1000/16).
#define NCLS 91
#define NFG 90
#define NDET 100
#define FDIM 1024
#define CAP 4096           // candidate buffer per image (40x headroom over expected ~100-400)
#define NBUK 4096          // histogram buckets = top 12 bits of score float bits
#define BBOX_CLIP 4.135166556742356f

// ---------------- K0: zero histogram + counters ----------------
__global__ void k_zero(unsigned* __restrict__ p, int n) {
    int i = blockIdx.x * 256 + threadIdx.x;
    if (i < n) p[i] = 0u;
}

// ---------------- K1: per-row softmax stats (max, sum) ----------------
// one wave (64 lanes) per row of 91 logits
__global__ void k_softmax_stats(const float* __restrict__ logits,
                                float* __restrict__ rowmax,
                                float* __restrict__ rowsum, int N) {
    int row = (blockIdx.x * blockDim.x + threadIdx.x) >> 6;
    int lane = threadIdx.x & 63;
    if (row >= N) return;
    const float* r = logits + (long long)row * NCLS;
    float l1 = r[lane];                                  // lanes 0..63 all valid (91 cols)
    float l2 = (lane < NCLS - 64) ? r[64 + lane] : -INFINITY;
    float m = fmaxf(l1, l2);
    #pragma unroll
    for (int off = 32; off; off >>= 1) m = fmaxf(m, __shfl_xor(m, off));
    float e = expf(l1 - m) + ((lane < NCLS - 64) ? expf(l2 - m) : 0.0f);
    #pragma unroll
    for (int off = 32; off; off >>= 1) e += __shfl_xor(e, off);
    if (lane == 0) { rowmax[row] = m; rowsum[row] = e; }
}

// ---------------- K2: per-image histogram of score-key top 12 bits ----------------
// grid = B * bpi blocks; each block does 4096 elements of one image via LDS hist
__global__ void k_hist(const float* __restrict__ logits,
                       const float* __restrict__ rowmax,
                       const float* __restrict__ rowsum,
                       unsigned* __restrict__ ghist, int P, int bpi) {
    __shared__ unsigned h[NBUK];
    for (int b = threadIdx.x; b < NBUK; b += 256) h[b] = 0u;
    __syncthreads();
    int img = blockIdx.x / bpi;
    int blk = blockIdx.x % bpi;
    int base = blk * 4096;
    int rowbase = img * P;
    int elems = P * NFG;
    #pragma unroll
    for (int i = 0; i < 16; i++) {
        int e = base + i * 256 + threadIdx.x;
        if (e < elems) {
            int p = e / NFG, cm = e - p * NFG;
            int rr = rowbase + p;
            float sc = expf(logits[(long long)rr * NCLS + cm + 1] - rowmax[rr]) / rowsum[rr];
            unsigned key = __float_as_uint(sc);   // scores in (0,1): bits are monotone
            atomicAdd(&h[key >> 20], 1u);
        }
    }
    __syncthreads();
    for (int b = threadIdx.x; b < NBUK; b += 256)
        if (h[b]) atomicAdd(&ghist[img * NBUK + b], h[b]);
}

// ---------------- K3: find threshold bucket (cum-from-top >= 100) ----------------
__global__ void k_threshold(const unsigned* __restrict__ ghist,
                            unsigned* __restrict__ lowBound) {
    __shared__ unsigned partial[256];
    __shared__ unsigned suffix[257];
    int img = blockIdx.x;
    const unsigned* h = ghist + img * NBUK;
    unsigned local[16];
    unsigned sum = 0;
    #pragma unroll
    for (int i = 0; i < 16; i++) { local[i] = h[threadIdx.x * 16 + i]; sum += local[i]; }
    partial[threadIdx.x] = sum;
    __syncthreads();
    if (threadIdx.x == 0) {
        unsigned run = 0;
        suffix[256] = 0;
        for (int t = 255; t >= 0; t--) { run += partial[t]; suffix[t] = run; }
    }
    __syncthreads();
    unsigned run = suffix[threadIdx.x + 1];   // count strictly above my chunk
    #pragma unroll
    for (int i = 15; i >= 0; i--) {
        unsigned prev = run;
        run += local[i];
        if (run >= NDET && prev < NDET)
            lowBound[img] = ((unsigned)(threadIdx.x * 16 + i)) << 20;
    }
}

// ---------------- K4: collect candidates >= threshold ----------------
__global__ void k_collect(const float* __restrict__ logits,
                          const float* __restrict__ rowmax,
                          const float* __restrict__ rowsum,
                          const unsigned* __restrict__ lowBound,
                          unsigned* __restrict__ gcnt,
                          unsigned long long* __restrict__ cand, int P, int bpi) {
    int img = blockIdx.x / bpi;
    int blk = blockIdx.x % bpi;
    unsigned lb = lowBound[img];
    int base = blk * 4096;
    int rowbase = img * P;
    int elems = P * NFG;
    #pragma unroll
    for (int i = 0; i < 16; i++) {
        int e = base + i * 256 + threadIdx.x;
        if (e < elems) {
            int p = e / NFG, cm = e - p * NFG;
            int rr = rowbase + p;
            float sc = expf(logits[(long long)rr * NCLS + cm + 1] - rowmax[rr]) / rowsum[rr];
            unsigned key = __float_as_uint(sc);
            if (key >= lb) {
                unsigned pos = atomicAdd(&gcnt[img], 1u);
                if (pos < CAP)
                    cand[(long long)img * CAP + pos] =
                        ((unsigned long long)key << 32) | (unsigned)(0xFFFFFFFFu - (unsigned)e);
            }
        }
    }
}

// ---------------- K5: per-image bitonic sort of candidates + box decode ----------------
__global__ __launch_bounds__(1024) void k_sort_boxes(
        const unsigned long long* __restrict__ cand,
        const unsigned* __restrict__ gcnt,
        const float* __restrict__ reg,
        const float* __restrict__ props,
        const int* __restrict__ pH, const int* __restrict__ pW,
        float* __restrict__ outBoxes, unsigned* __restrict__ keepRow, int P) {
    __shared__ unsigned long long keys[CAP];
    int img = blockIdx.x;
    unsigned cnt = gcnt[img];
    if (cnt > CAP) cnt = CAP;
    for (int i = threadIdx.x; i < CAP; i += 1024)
        keys[i] = (i < (int)cnt) ? cand[(long long)img * CAP + i] : 0ULL;
    __syncthreads();
    // ascending bitonic sort; top-100 ends at indices CAP-1 .. CAP-100
    for (int k = 2; k <= CAP; k <<= 1) {
        for (int j = k >> 1; j > 0; j >>= 1) {
            for (int i = threadIdx.x; i < CAP; i += 1024) {
                int ixj = i ^ j;
                if (ixj > i) {
                    bool up = ((i & k) == 0);
                    unsigned long long a = keys[i], b = keys[ixj];
                    if ((a > b) == up) { keys[i] = b; keys[ixj] = a; }
                }
            }
            __syncthreads();
        }
    }
    if (threadIdx.x < NDET) {
        unsigned long long key = keys[CAP - 1 - threadIdx.x];
        unsigned e = 0xFFFFFFFFu - (unsigned)(key & 0xFFFFFFFFull);
        int p = e / NFG, cm = e - p * NFG, c = cm + 1;
        long long r = (long long)img * P + p;
        float x1 = props[r * 4 + 0], y1 = props[r * 4 + 1];
        float x2 = props[r * 4 + 2], y2 = props[r * 4 + 3];
        float w = x2 - x1, hgt = y2 - y1;
        float cx = x1 + 0.5f * w, cy = y1 + 0.5f * hgt;
        const float* rr = reg + r * (4 * NCLS) + 4 * c;
        float dx = rr[0] / 10.0f, dy = rr[1] / 10.0f;
        float dw = fminf(rr[2] / 5.0f, BBOX_CLIP);
        float dh = fminf(rr[3] / 5.0f, BBOX_CLIP);
        float pcx = dx * w + cx, pcy = dy * hgt + cy;
        float pw_ = expf(dw) * w, ph_ = expf(dh) * hgt;
        float bx1 = pcx - 0.5f * pw_, by1 = pcy - 0.5f * ph_;
        float bx2 = pcx + 0.5f * pw_, by2 = pcy + 0.5f * ph_;
        float W = (float)(*pW), H = (float)(*pH);
        bx1 = fminf(fmaxf(bx1, 0.0f), W);
        bx2 = fminf(fmaxf(bx2, 0.0f), W);
        by1 = fminf(fmaxf(by1, 0.0f), H);
        by2 = fminf(fmaxf(by2, 0.0f), H);
        int o = (img * NDET + threadIdx.x) * 4;
        outBoxes[o + 0] = bx1 / H;
        outBoxes[o + 1] = by1 / H;
        outBoxes[o + 2] = bx2 / H;
        outBoxes[o + 3] = by2 / H;
        keepRow[img * NDET + threadIdx.x] = (unsigned)r;
    }
}

// ---------------- K6: feature gather ----------------
__global__ void k_feats(const float* __restrict__ feats,
                        const unsigned* __restrict__ keepRow,
                        float* __restrict__ outF) {
    int det = blockIdx.x;
    long long r = keepRow[det];
    const float4* src = (const float4*)(feats + r * FDIM);
    float4* dst = (float4*)(outF + (long long)det * FDIM);
    dst[threadIdx.x] = src[threadIdx.x];
}

extern "C" void kernel_launch(void* const* d_in, const int* in_sizes, int n_in,
                              void* d_out, int out_size, void* d_ws, size_t ws_size,
                              hipStream_t stream) {
    const float* logits = (const float*)d_in[0];
    const float* reg    = (const float*)d_in[1];
    const float* props  = (const float*)d_in[2];
    const float* feats  = (const float*)d_in[3];
    const int*   pH     = (const int*)d_in[5];
    const int*   pW     = (const int*)d_in[6];

    int N = in_sizes[0] / NCLS;                 // total proposals (B*P)
    int B = out_size / (NDET * (4 + FDIM));     // 822400 / 102800 = 8
    int P = N / B;
    int elems = P * NFG;
    int bpi = (elems + 4095) / 4096;            // blocks per image for hist/collect

    // workspace layout
    char* ws = (char*)d_ws;
    float* rowmax = (float*)ws;                           // N floats
    float* rowsum = rowmax + N;                           // N floats
    unsigned* ghist = (unsigned*)(rowsum + N);            // B*NBUK
    unsigned* gcnt  = ghist + (size_t)B * NBUK;           // B   (contiguous after ghist)
    unsigned* lowB  = gcnt + B;                           // B
    size_t off = (size_t)(2 * N) * 4 + (size_t)(B * NBUK + 2 * B) * 4;
    off = (off + 7) & ~(size_t)7;
    unsigned long long* cand = (unsigned long long*)(ws + off);  // B*CAP u64
    unsigned* keepRow = (unsigned*)(cand + (size_t)B * CAP);     // B*NDET

    float* outBoxes = (float*)d_out;
    float* outFeats = outBoxes + (size_t)B * NDET * 4;

    int nzero = B * NBUK + B;  // ghist + gcnt
    k_zero<<<(nzero + 255) / 256, 256, 0, stream>>>(ghist, nzero);
    k_softmax_stats<<<(N + 3) / 4, 256, 0, stream>>>(logits, rowmax, rowsum, N);
    k_hist<<<B * bpi, 256, 0, stream>>>(logits, rowmax, rowsum, ghist, P, bpi);
    k_threshold<<<B, 256, 0, stream>>>(ghist, lowB);
    k_collect<<<B * bpi, 256, 0, stream>>>(logits, rowmax, rowsum, lowB, gcnt, cand, P, bpi);
    k_sort_boxes<<<B, 1024, 0, stream>>>(cand, gcnt, reg, props, pH, pW, outBoxes, keepRow, P);
    k_feats<<<B * NDET, 256, 0, stream>>>(feats, keepRow, outFeats);
}

// Round 2
// 243.061 us; speedup vs baseline: 1.1823x; 1.1823x over previous
//
#include <hip/hip_runtime.h>
#include <hip/hip_bf16.h>

// Faster-RCNN box-head postprocess: softmax(91) -> exact top-100 of P*90 scores
// per image (argsort order incl. stable tie-break) -> decode/clip/normalize the
// 100 boxes -> gather 1024-d features.
// Strategy: radix-select via 12-bit histogram of monotone float bits, then sort
// only the ~100-300 surviving candidates.
#define NCLS 91
#define NFG 90
#define NDET 100
#define FDIM 1024
#define CAP 4096           // candidate overflow cap per image
#define NBUK 4096          // histogram buckets = top 12 bits of score float bits
#define BBOX_CLIP 4.135166556742356f
#define RPB 32             // rows per block in k_softhist (4 waves x 8 rows)

// ---------------- K0: zero histogram + counters ----------------
__global__ void k_zero(unsigned* __restrict__ p, int n) {
    int i = blockIdx.x * 256 + threadIdx.x;
    if (i < n) p[i] = 0u;
}

// ---------------- K1: fused softmax stats + score histogram ----------------
// One wave per row: reduce max & sum over 91 logits, emit rowoff = m + log(s)
// (score = exp(logit - rowoff)), histogram the 90 fg keys from registers.
__global__ __launch_bounds__(256) void k_softhist(const float* __restrict__ logits,
                                                  float* __restrict__ rowoff,
                                                  unsigned* __restrict__ ghist, int P) {
    __shared__ unsigned h[NBUK];
    for (int b = threadIdx.x; b < NBUK; b += 256) h[b] = 0u;
    __syncthreads();
    int bpi = (P + RPB - 1) / RPB;
    int img = blockIdx.x / bpi;
    int blk = blockIdx.x % bpi;
    int wave = threadIdx.x >> 6, lane = threadIdx.x & 63;
    #pragma unroll
    for (int it = 0; it < RPB / 4; it++) {
        int rl = blk * RPB + it * 4 + wave;       // row within image
        if (rl >= P) break;
        long long row = (long long)img * P + rl;
        const float* r = logits + row * NCLS;
        float l1 = r[lane];                       // classes 0..63
        float l2 = (lane < NCLS - 64) ? r[64 + lane] : -INFINITY;  // classes 64..90
        float m = fmaxf(l1, l2);
        #pragma unroll
        for (int o = 32; o; o >>= 1) m = fmaxf(m, __shfl_xor(m, o));
        float e = expf(l1 - m) + ((lane < NCLS - 64) ? expf(l2 - m) : 0.0f);
        #pragma unroll
        for (int o = 32; o; o >>= 1) e += __shfl_xor(e, o);
        float off = m + logf(e);                  // identical bits across lanes
        if (lane == 0) rowoff[row] = off;
        if (lane >= 1) {                          // fg classes 1..63
            unsigned k1 = __float_as_uint(expf(l1 - off));
            atomicAdd(&h[k1 >> 20], 1u);
        }
        if (lane < NCLS - 64) {                   // fg classes 64..90
            unsigned k2 = __float_as_uint(expf(l2 - off));
            atomicAdd(&h[k2 >> 20], 1u);
        }
    }
    __syncthreads();
    for (int b = threadIdx.x; b < NBUK; b += 256)
        if (h[b]) atomicAdd(&ghist[img * NBUK + b], h[b]);
}

// ---------------- K2: find threshold bucket (cum-from-top >= 100) ----------------
__global__ void k_threshold(const unsigned* __restrict__ ghist,
                            unsigned* __restrict__ lowBound) {
    __shared__ unsigned partial[256];
    __shared__ unsigned suffix[257];
    int img = blockIdx.x;
    const unsigned* h = ghist + img * NBUK;
    unsigned local[16];
    unsigned sum = 0;
    #pragma unroll
    for (int i = 0; i < 16; i++) { local[i] = h[threadIdx.x * 16 + i]; sum += local[i]; }
    partial[threadIdx.x] = sum;
    __syncthreads();
    if (threadIdx.x == 0) {
        unsigned run = 0;
        suffix[256] = 0;
        for (int t = 255; t >= 0; t--) { run += partial[t]; suffix[t] = run; }
    }
    __syncthreads();
    unsigned run = suffix[threadIdx.x + 1];   // count strictly above my chunk
    #pragma unroll
    for (int i = 15; i >= 0; i--) {
        unsigned prev = run;
        run += local[i];
        if (run >= NDET && prev < NDET)
            lowBound[img] = ((unsigned)(threadIdx.x * 16 + i)) << 20;
    }
}

// ---------------- K3: collect candidates >= threshold ----------------
__global__ void k_collect(const float* __restrict__ logits,
                          const float* __restrict__ rowoff,
                          const unsigned* __restrict__ lowBound,
                          unsigned* __restrict__ gcnt,
                          unsigned long long* __restrict__ cand, int P, int bpi) {
    int img = blockIdx.x / bpi;
    int blk = blockIdx.x % bpi;
    unsigned lb = lowBound[img];
    int base = blk * 4096;
    int rowbase = img * P;
    int elems = P * NFG;
    #pragma unroll
    for (int i = 0; i < 16; i++) {
        int e = base + i * 256 + threadIdx.x;
        if (e < elems) {
            int p = e / NFG, cm = e - p * NFG;
            long long rr = rowbase + p;
            float sc = expf(logits[rr * NCLS + cm + 1] - rowoff[rr]);
            unsigned key = __float_as_uint(sc);
            if (key >= lb) {
                unsigned pos = atomicAdd(&gcnt[img], 1u);
                if (pos < CAP)
                    cand[(long long)img * CAP + pos] =
                        ((unsigned long long)key << 32) | (unsigned)(0xFFFFFFFFu - (unsigned)e);
            }
        }
    }
}

// ---------------- K4: per-image bitonic sort (dynamic size) + box decode ----------------
__global__ __launch_bounds__(256) void k_sort_boxes(
        const unsigned long long* __restrict__ cand,
        const unsigned* __restrict__ gcnt,
        const float* __restrict__ reg,
        const float* __restrict__ props,
        const int* __restrict__ pH, const int* __restrict__ pW,
        float* __restrict__ outBoxes, unsigned* __restrict__ keepRow, int P) {
    __shared__ unsigned long long keys[CAP];
    int img = blockIdx.x;
    unsigned cnt = gcnt[img];
    if (cnt > CAP) cnt = CAP;
    int n = 128;                       // sort size = next_pow2(max(cnt,128))
    while (n < (int)cnt) n <<= 1;
    for (int i = threadIdx.x; i < n; i += 256)
        keys[i] = (i < (int)cnt) ? cand[(long long)img * CAP + i] : 0ULL;
    __syncthreads();
    // ascending bitonic sort of n elements; top-100 ends at n-1 .. n-100
    for (int k = 2; k <= n; k <<= 1) {
        for (int j = k >> 1; j > 0; j >>= 1) {
            for (int i = threadIdx.x; i < n; i += 256) {
                int ixj = i ^ j;
                if (ixj > i) {
                    bool up = ((i & k) == 0);
                    unsigned long long a = keys[i], b = keys[ixj];
                    if ((a > b) == up) { keys[i] = b; keys[ixj] = a; }
                }
            }
            __syncthreads();
        }
    }
    if (threadIdx.x < NDET) {
        unsigned long long key = keys[n - 1 - threadIdx.x];
        unsigned e = 0xFFFFFFFFu - (unsigned)(key & 0xFFFFFFFFull);
        int p = e / NFG, cm = e - p * NFG, c = cm + 1;
        long long r = (long long)img * P + p;
        float x1 = props[r * 4 + 0], y1 = props[r * 4 + 1];
        float x2 = props[r * 4 + 2], y2 = props[r * 4 + 3];
        float w = x2 - x1, hgt = y2 - y1;
        float cx = x1 + 0.5f * w, cy = y1 + 0.5f * hgt;
        const float* rr = reg + r * (4 * NCLS) + 4 * c;
        float dx = rr[0] / 10.0f, dy = rr[1] / 10.0f;
        float dw = fminf(rr[2] / 5.0f, BBOX_CLIP);
        float dh = fminf(rr[3] / 5.0f, BBOX_CLIP);
        float pcx = dx * w + cx, pcy = dy * hgt + cy;
        float pw_ = expf(dw) * w, ph_ = expf(dh) * hgt;
        float bx1 = pcx - 0.5f * pw_, by1 = pcy - 0.5f * ph_;
        float bx2 = pcx + 0.5f * pw_, by2 = pcy + 0.5f * ph_;
        float W = (float)(*pW), H = (float)(*pH);
        bx1 = fminf(fmaxf(bx1, 0.0f), W);
        bx2 = fminf(fmaxf(bx2, 0.0f), W);
        by1 = fminf(fmaxf(by1, 0.0f), H);
        by2 = fminf(fmaxf(by2, 0.0f), H);
        int o = (img * NDET + threadIdx.x) * 4;
        outBoxes[o + 0] = bx1 / H;
        outBoxes[o + 1] = by1 / H;
        outBoxes[o + 2] = bx2 / H;
        outBoxes[o + 3] = by2 / H;
        keepRow[img * NDET + threadIdx.x] = (unsigned)r;
    }
}

// ---------------- K5: feature gather ----------------
__global__ void k_feats(const float* __restrict__ feats,
                        const unsigned* __restrict__ keepRow,
                        float* __restrict__ outF) {
    int det = blockIdx.x;
    long long r = keepRow[det];
    const float4* src = (const float4*)(feats + r * FDIM);
    float4* dst = (float4*)(outF + (long long)det * FDIM);
    dst[threadIdx.x] = src[threadIdx.x];
}

extern "C" void kernel_launch(void* const* d_in, const int* in_sizes, int n_in,
                              void* d_out, int out_size, void* d_ws, size_t ws_size,
                              hipStream_t stream) {
    const float* logits = (const float*)d_in[0];
    const float* reg    = (const float*)d_in[1];
    const float* props  = (const float*)d_in[2];
    const float* feats  = (const float*)d_in[3];
    const int*   pH     = (const int*)d_in[5];
    const int*   pW     = (const int*)d_in[6];

    int N = in_sizes[0] / NCLS;                 // total proposals (B*P)
    int B = out_size / (NDET * (4 + FDIM));     // 8
    int P = N / B;
    int elems = P * NFG;
    int bpi_hist = (P + RPB - 1) / RPB;         // softhist blocks per image
    int bpi_col  = (elems + 4095) / 4096;       // collect blocks per image

    // workspace layout
    char* ws = (char*)d_ws;
    float* rowoff = (float*)ws;                           // N floats
    unsigned* ghist = (unsigned*)(rowoff + N);            // B*NBUK
    unsigned* gcnt  = ghist + (size_t)B * NBUK;           // B (contiguous after ghist)
    unsigned* lowB  = gcnt + B;                           // B
    size_t off = (size_t)N * 4 + (size_t)(B * NBUK + 2 * B) * 4;
    off = (off + 7) & ~(size_t)7;
    unsigned long long* cand = (unsigned long long*)(ws + off);  // B*CAP u64
    unsigned* keepRow = (unsigned*)(cand + (size_t)B * CAP);     // B*NDET

    float* outBoxes = (float*)d_out;
    float* outFeats = outBoxes + (size_t)B * NDET * 4;

    int nzero = B * NBUK + B;  // ghist + gcnt
    k_zero<<<(nzero + 255) / 256, 256, 0, stream>>>(ghist, nzero);
    k_softhist<<<B * bpi_hist, 256, 0, stream>>>(logits, rowoff, ghist, P);
    k_threshold<<<B, 256, 0, stream>>>(ghist, lowB);
    k_collect<<<B * bpi_col, 256, 0, stream>>>(logits, rowoff, lowB, gcnt, cand, P, bpi_col);
    k_sort_boxes<<<B, 256, 0, stream>>>(cand, gcnt, reg, props, pH, pW, outBoxes, keepRow, P);
    k_feats<<<B * NDET, 256, 0, stream>>>(feats, keepRow, outFeats);
}